// Round 12
// baseline (104.806 us; speedup 1.0000x reference)
//
#include <hip/hip_runtime.h>
#include <cstddef>

#define HDIM 2048
#define NE 64
#define TOPK 4
#define BM2 32

// ---------- transpose+scale pre-pass: wt[k][e] = w[e][k] * scale[k] ----------
__global__ __launch_bounds__(256) void transpose_w_kernel(
    const float* __restrict__ w, const float* __restrict__ scale,
    float* __restrict__ wt)
{
    __shared__ float Wl[64][65];
    const int tid = threadIdx.x;
    const int k0 = blockIdx.x * 64;          // grid = HDIM/64 = 32
    #pragma unroll
    for (int q = 0; q < 4; q++) {
        int f = tid + 256 * q;
        int e = f >> 4;
        int k4 = (f & 15) * 4;
        float4 v = *(const float4*)(w + (size_t)e * HDIM + k0 + k4);
        Wl[e][k4 + 0] = v.x; Wl[e][k4 + 1] = v.y;
        Wl[e][k4 + 2] = v.z; Wl[e][k4 + 3] = v.w;
    }
    __syncthreads();
    #pragma unroll
    for (int q = 0; q < 4; q++) {
        int f = tid + 256 * q;
        int k = f >> 4;
        int e4 = (f & 15) * 4;
        float s = scale[k0 + k];
        float4 v;
        v.x = Wl[e4 + 0][k] * s; v.y = Wl[e4 + 1][k] * s;
        v.z = Wl[e4 + 2][k] * s; v.w = Wl[e4 + 3][k] * s;
        *(float4*)(wt + (size_t)(k0 + k) * NE + e4) = v;
    }
}

// ---------- GEMM: A via wave-private LDS pane (broadcast+ssq), B DIRECT from ----------
// global (L1/L2-hot 512KB wt, float4 over experts = contiguous). DS instr per
// chunk halves vs r7-r11 (the measured per-CU bottleneck: KS=16 at 2 blocks/CU
// gave zero gain -> DS-throughput-bound, not latency-bound).
template<int KS>
__global__ __launch_bounds__(512) void gemm12_kernel(
    const float* __restrict__ x, const float* __restrict__ wt,
    float* __restrict__ sp0,     // partial scores ks=0 (probs region)
    float* __restrict__ spws,    // partial scores ks=1..KS-1
    float* __restrict__ sq,      // [KS][tokens] partial ssq
    int tokens)
{
    constexpr int KR = HDIM / KS;      // 256 @ KS=8
    constexpr int NCH = KR / 8;        // 8-k chunks
    __shared__ float As_all[8][64][12];  // per-wave A pane only (24 KB total)

    const int tid = threadIdx.x;
    const int w = tid >> 6;            // wave id
    const int l = tid & 63;
    const int ks = blockIdx.x & (KS - 1);
    const int tile = blockIdx.x / KS;
    const int tokw0 = tile * 512 + w * 64;
    const int k0 = ks * KR;

    float (*As)[12] = As_all[w];

    const int tr = l & 7;              // token-octet index (compute)
    const int ec = l >> 3;             // expert-octet (compute)

    // A staging: lane -> (tokens atok, atok+32; k-half ah)  [r7-verified]
    const int atok = l >> 1;
    const int ah = l & 1;
    const int aswz = ah ^ ((l >> 4) & 1);
    const float* xa0 = x + (size_t)(tokw0 + atok) * HDIM + k0 + 4 * ah;
    const float* xa1 = xa0 + (size_t)32 * HDIM;

    // B direct-read base: lane covers experts 8ec..8ec+7 (two float4 per k-row)
    const float* wb = wt + (size_t)k0 * NE + 8 * ec;

    float acc[8][8];
    #pragma unroll
    for (int i = 0; i < 8; i++)
        #pragma unroll
        for (int j = 0; j < 8; j++) acc[i][j] = 0.f;
    float ssq0 = 0.f, ssq1 = 0.f;

    float4 pa0, pa1;
    auto LOADA = [&](int c) {
        pa0 = *(const float4*)(xa0 + c * 8);
        pa1 = *(const float4*)(xa1 + c * 8);
    };
    auto STOREA = [&]() {
        *(float4*)&As[atok][4 * aswz] = pa0;
        *(float4*)&As[32 + atok][4 * aswz] = pa1;
        ssq0 += pa0.x*pa0.x + pa0.y*pa0.y + pa0.z*pa0.z + pa0.w*pa0.w;
        ssq1 += pa1.x*pa1.x + pa1.y*pa1.y + pa1.z*pa1.z + pa1.w*pa1.w;
    };

    LOADA(0);
    STOREA();                          // vmcnt wait inserted by compiler

    const float* wc = wb;              // advances 8*NE per chunk
    for (int c = 0; c < NCH; ++c, wc += 8 * NE) {
        if (c + 1 < NCH) LOADA(c + 1); // next A chunk in flight under compute
        #pragma unroll
        for (int kq = 0; kq < 2; ++kq) {
            // B: 8 global float4 loads (k-rows 4kq..4kq+3, lo/hi expert quads)
            float4 Bk[4][2];
            #pragma unroll
            for (int kk = 0; kk < 4; ++kk) {
                Bk[kk][0] = *(const float4*)(wc + (size_t)(4 * kq + kk) * NE);
                Bk[kk][1] = *(const float4*)(wc + (size_t)(4 * kq + kk) * NE + 4);
            }
            // A: 8 LDS float4 reads (token rows, conflict-free, 8-way broadcast)
            float4 Ai[8];
            #pragma unroll
            for (int i = 0; i < 8; ++i)
                Ai[i] = *(const float4*)&As[8 * i + tr][4 * (kq ^ (i & 1))];
            // FMA: 256 per kq
            #pragma unroll
            for (int kk = 0; kk < 4; ++kk) {
                #pragma unroll
                for (int h = 0; h < 2; ++h) {
                    float4 Bv = Bk[kk][h];
                    #pragma unroll
                    for (int i = 0; i < 8; ++i) {
                        float av = (kk == 0) ? Ai[i].x : (kk == 1) ? Ai[i].y
                                 : (kk == 2) ? Ai[i].z : Ai[i].w;
                        acc[i][4*h + 0] = fmaf(av, Bv.x, acc[i][4*h + 0]);
                        acc[i][4*h + 1] = fmaf(av, Bv.y, acc[i][4*h + 1]);
                        acc[i][4*h + 2] = fmaf(av, Bv.z, acc[i][4*h + 2]);
                        acc[i][4*h + 3] = fmaf(av, Bv.w, acc[i][4*h + 3]);
                    }
                }
            }
        }
        if (c + 1 < NCH) {
            // chunk-c ds_reads must land before pane overwrite (same wave, in order)
            asm volatile("s_waitcnt lgkmcnt(0)" ::: "memory");
            STOREA();
        }
    }

    // ssq: combine the two k-half lanes of each token (lanes 2t, 2t+1)
    ssq0 += __shfl_xor(ssq0, 1, 64);
    ssq1 += __shfl_xor(ssq1, 1, 64);
    if (ah == 0) {
        sq[(size_t)ks * tokens + tokw0 + atok] = ssq0;
        sq[(size_t)ks * tokens + tokw0 + 32 + atok] = ssq1;
    }

    float* sp = (ks == 0) ? sp0 : (spws + (size_t)(ks - 1) * tokens * NE);
    #pragma unroll
    for (int i = 0; i < 8; ++i) {      // token 8i+tr, experts 8ec..8ec+7
        size_t off = (size_t)(tokw0 + 8 * i + tr) * NE + 8 * ec;
        float4 v0 = {acc[i][0], acc[i][1], acc[i][2], acc[i][3]};
        float4 v1 = {acc[i][4], acc[i][5], acc[i][6], acc[i][7]};
        *(float4*)(sp + off) = v0;
        *(float4*)(sp + off + 4) = v1;
    }
}

// ---------- finisher: tree-sum KS partials, rmsnorm, softmax, top-4 ----------
template<int KS>
__global__ __launch_bounds__(256) void finish12_kernel(
    const float* __restrict__ sp0, const float* __restrict__ spws,
    const float* __restrict__ sq, const float* __restrict__ pes,
    float* __restrict__ probs, float* __restrict__ tkw, float* __restrict__ tki,
    int tokens)
{
    __shared__ float Sl[BM2 * 65];
    __shared__ float Pl[BM2 * 65];
    __shared__ float FN[BM2];
    __shared__ float RS[BM2];

    const int tid = threadIdx.x;
    const int tok0 = blockIdx.x * BM2;

    if (tid < BM2) {
        float q[KS];
        #pragma unroll
        for (int i = 0; i < KS; i++) q[i] = sq[(size_t)i * tokens + tok0 + tid];
        #pragma unroll
        for (int st = 1; st < KS; st <<= 1)
            #pragma unroll
            for (int i = 0; i < KS; i += 2 * st) q[i] += q[i + st];
        FN[tid] = rsqrtf(q[0] * (1.0f / HDIM) + 1e-6f) * 0.022097086912079612f;
    }
    __syncthreads();

    #pragma unroll
    for (int qq = 0; qq < 2; qq++) {
        int f = tid + 256 * qq;
        int m = f >> 4;
        int e4 = f & 15;
        float4 t[KS];
        t[0] = ((const float4*)sp0)[(size_t)(tok0 + m) * (NE / 4) + e4];
        #pragma unroll
        for (int i = 1; i < KS; i++)
            t[i] = ((const float4*)(spws + (size_t)(i - 1) * tokens * NE))
                       [(size_t)(tok0 + m) * (NE / 4) + e4];
        #pragma unroll
        for (int st = 1; st < KS; st <<= 1)
            #pragma unroll
            for (int i = 0; i < KS; i += 2 * st) {
                t[i].x += t[i + st].x; t[i].y += t[i + st].y;
                t[i].z += t[i + st].z; t[i].w += t[i + st].w;
            }
        float fn = FN[m];
        int base = m * 65 + e4 * 4;
        Sl[base + 0] = t[0].x * fn; Sl[base + 1] = t[0].y * fn;
        Sl[base + 2] = t[0].z * fn; Sl[base + 3] = t[0].w * fn;
    }
    __syncthreads();

    if (tid < BM2) {
        const int m = tid;
        float mx = -3.0e38f;
        for (int e = 0; e < NE; e++) mx = fmaxf(mx, Sl[m * 65 + e]);
        float sum = 0.f;
        for (int e = 0; e < NE; e++) {
            float p = __expf(Sl[m * 65 + e] - mx);
            Pl[m * 65 + e] = p;
            sum += p;
        }
        RS[m] = 1.0f / sum;
    }
    __syncthreads();

    #pragma unroll
    for (int qq = 0; qq < 2; qq++) {
        int f = tid + 256 * qq;
        int m = f >> 4;
        int e0 = (f & 15) * 4;
        float rs = RS[m];
        float4 pv;
        pv.x = Pl[m * 65 + e0 + 0] * rs;
        pv.y = Pl[m * 65 + e0 + 1] * rs;
        pv.z = Pl[m * 65 + e0 + 2] * rs;
        pv.w = Pl[m * 65 + e0 + 3] * rs;
        *(float4*)&probs[(size_t)(tok0 + m) * NE + e0] = pv;
    }

    if (tid < BM2) {                   // destructive top-4, lowest-index ties
        const int m = tid;
        float wv[TOPK]; int idx[TOPK];
        float wsum = 0.f;
        #pragma unroll
        for (int kk = 0; kk < TOPK; ++kk) {
            float best = -3.0e38f; int bi = 0;
            for (int e = 0; e < NE; e++) {
                float v = Sl[m * 65 + e];
                if (v > best) { best = v; bi = e; }
            }
            Sl[m * 65 + bi] = -3.4e38f;
            float p = Pl[m * 65 + bi];
            wv[kk] = p; idx[kk] = bi; wsum += p;
        }
        float inv = 1.0f / wsum;
        size_t ob = (size_t)(tok0 + m) * TOPK;
        #pragma unroll
        for (int kk = 0; kk < TOPK; kk++) {
            tkw[ob + kk] = wv[kk] * inv * pes[idx[kk]];
            tki[ob + kk] = (float)idx[kk];   // harness reads flat buffer as float32
        }
    }
}

extern "C" void kernel_launch(void* const* d_in, const int* in_sizes, int n_in,
                              void* d_out, int out_size, void* d_ws, size_t ws_size,
                              hipStream_t stream) {
    const float* x     = (const float*)d_in[0];
    const float* w     = (const float*)d_in[1];
    const float* scale = (const float*)d_in[2];
    const float* pes   = (const float*)d_in[3];
    const int tokens = in_sizes[0] / HDIM;      // 16384

    float* probs = (float*)d_out;
    float* tkw   = probs + (size_t)tokens * NE;
    float* tki   = tkw + (size_t)tokens * TOPK;

    const size_t wtN = (size_t)HDIM * NE;
    const size_t spN = (size_t)tokens * NE;
    const size_t need8 = (wtN + 7 * spN + (size_t)8 * tokens) * sizeof(float);
    const int KS = (ws_size >= need8) ? 8 : 4;

    float* wt   = (float*)d_ws;
    float* spws = wt + wtN;
    float* sq   = spws + (size_t)(KS - 1) * spN;
    float* sp0  = probs;                        // overwritten by finisher

    transpose_w_kernel<<<HDIM / 64, 256, 0, stream>>>(w, scale, wt);

    const int grid1 = (tokens / 512) * KS;      // 256 @ KS=8 -> 1 block/CU
    if (KS == 8)
        gemm12_kernel<8><<<grid1, 512, 0, stream>>>(x, wt, sp0, spws, sq, tokens);
    else
        gemm12_kernel<4><<<grid1, 512, 0, stream>>>(x, wt, sp0, spws, sq, tokens);

    const int grid2 = tokens / BM2;             // 512
    if (KS == 8)
        finish12_kernel<8><<<grid2, 256, 0, stream>>>(sp0, spws, sq, pes, probs, tkw, tki, tokens);
    else
        finish12_kernel<4><<<grid2, 256, 0, stream>>>(sp0, spws, sq, pes, probs, tkw, tki, tokens);
}

// Round 13
// 95.932 us; speedup vs baseline: 1.0925x; 1.0925x over previous
//
#include <hip/hip_runtime.h>
#include <cstddef>

#define HDIM 2048
#define NE 64
#define TOPK 4
#define BM2 32

// ---------- transpose+scale pre-pass: wt[k][e] = w[e][k] * scale[k] ----------
__global__ __launch_bounds__(256) void transpose_w_kernel(
    const float* __restrict__ w, const float* __restrict__ scale,
    float* __restrict__ wt)
{
    __shared__ float Wl[64][65];
    const int tid = threadIdx.x;
    const int k0 = blockIdx.x * 64;          // grid = HDIM/64 = 32
    #pragma unroll
    for (int q = 0; q < 4; q++) {
        int f = tid + 256 * q;
        int e = f >> 4;
        int k4 = (f & 15) * 4;
        float4 v = *(const float4*)(w + (size_t)e * HDIM + k0 + k4);
        Wl[e][k4 + 0] = v.x; Wl[e][k4 + 1] = v.y;
        Wl[e][k4 + 2] = v.z; Wl[e][k4 + 3] = v.w;
    }
    __syncthreads();
    #pragma unroll
    for (int q = 0; q < 4; q++) {
        int f = tid + 256 * q;
        int k = f >> 4;
        int e4 = (f & 15) * 4;
        float s = scale[k0 + k];
        float4 v;
        v.x = Wl[e4 + 0][k] * s; v.y = Wl[e4 + 1][k] * s;
        v.z = Wl[e4 + 2][k] * s; v.w = Wl[e4 + 3][k] * s;
        *(float4*)(wt + (size_t)(k0 + k) * NE + e4) = v;
    }
}

// ---------- GEMM: A via wave-private LDS pane, B direct-global with ----------
// kq-level register double-buffering (B for (c,kq) loaded during the previous
// FMA block -> latency covered; loads issue behind FMA issues, WAR-safe).
// No __syncthreads; one same-wave lgkmcnt before the 2-instr pane overwrite.
// (512,1): min 1 block/CU -> 256-VGPR cap for the ~185-reg live set (r10 lesson).
template<int KS>
__global__ __launch_bounds__(512, 1) void gemm13_kernel(
    const float* __restrict__ x, const float* __restrict__ wt,
    float* __restrict__ sp0,     // partial scores ks=0 (probs region)
    float* __restrict__ spws,    // partial scores ks=1..KS-1
    float* __restrict__ sq,      // [KS][tokens] partial ssq
    int tokens)
{
    constexpr int KR = HDIM / KS;      // 256 @ KS=8
    constexpr int NCH = KR / 8;        // 8-k chunks
    __shared__ float As_all[8][64][12];  // per-wave A pane (24 KB)

    const int tid = threadIdx.x;
    const int w = tid >> 6;
    const int l = tid & 63;
    const int ks = blockIdx.x & (KS - 1);
    const int tile = blockIdx.x / KS;
    const int tokw0 = tile * 512 + w * 64;
    const int k0 = ks * KR;

    float (*As)[12] = As_all[w];

    const int tr = l & 7;              // token-octet index (compute)
    const int ec = l >> 3;             // expert-octet (compute)

    // A staging: lane -> (tokens atok, atok+32; k-half ah)  [r7-verified]
    const int atok = l >> 1;
    const int ah = l & 1;
    const int aswz = ah ^ ((l >> 4) & 1);
    const float* xa0 = x + (size_t)(tokw0 + atok) * HDIM + k0 + 4 * ah;
    const float* xa1 = xa0 + (size_t)32 * HDIM;

    // B base: experts 8ec..8ec+7, k advances by rows of NE
    const float* wb = wt + (size_t)k0 * NE + 8 * ec;

    float acc[8][8];
    #pragma unroll
    for (int i = 0; i < 8; i++)
        #pragma unroll
        for (int j = 0; j < 8; j++) acc[i][j] = 0.f;
    float ssq0 = 0.f, ssq1 = 0.f;

    float4 pa0, pa1;
    float4 B0[4][2], B1[4][2];

#define LOADA(c) { pa0 = *(const float4*)(xa0 + (c) * 8); \
                   pa1 = *(const float4*)(xa1 + (c) * 8); }
#define STOREA() { \
        *(float4*)&As[atok][4 * aswz] = pa0; \
        *(float4*)&As[32 + atok][4 * aswz] = pa1; \
        ssq0 += pa0.x*pa0.x + pa0.y*pa0.y + pa0.z*pa0.z + pa0.w*pa0.w; \
        ssq1 += pa1.x*pa1.x + pa1.y*pa1.y + pa1.z*pa1.z + pa1.w*pa1.w; }
#define LOADB(B, roff) { _Pragma("unroll") \
        for (int kk = 0; kk < 4; ++kk) { \
            B[kk][0] = *(const float4*)(wb + (size_t)((roff) + kk) * NE); \
            B[kk][1] = *(const float4*)(wb + (size_t)((roff) + kk) * NE + 4); } }
#define FMABLK(B, kq) { \
        float4 Ai[8]; \
        _Pragma("unroll") \
        for (int i = 0; i < 8; ++i) \
            Ai[i] = *(const float4*)&As[8 * i + tr][4 * ((kq) ^ (i & 1))]; \
        _Pragma("unroll") \
        for (int kk = 0; kk < 4; ++kk) { \
            _Pragma("unroll") \
            for (int h = 0; h < 2; ++h) { \
                float4 Bv = B[kk][h]; \
                _Pragma("unroll") \
                for (int i = 0; i < 8; ++i) { \
                    float av = (kk == 0) ? Ai[i].x : (kk == 1) ? Ai[i].y \
                             : (kk == 2) ? Ai[i].z : Ai[i].w; \
                    acc[i][4*h + 0] = fmaf(av, Bv.x, acc[i][4*h + 0]); \
                    acc[i][4*h + 1] = fmaf(av, Bv.y, acc[i][4*h + 1]); \
                    acc[i][4*h + 2] = fmaf(av, Bv.z, acc[i][4*h + 2]); \
                    acc[i][4*h + 3] = fmaf(av, Bv.w, acc[i][4*h + 3]); \
                } \
            } \
        } }

    LOADA(0);
    STOREA();                          // vmcnt wait inserted by compiler
    LOADB(B0, 0);                      // chunk 0, kq 0 (rows 0-3)
    LOADB(B1, 4);                      // chunk 0, kq 1 (rows 4-7)

    for (int c = 0; c < NCH; ++c) {
        const int r8 = 8 * c;
        if (c + 1 < NCH) LOADA(c + 1);     // next A chunk in flight
        FMABLK(B0, 0);                     // B0 loaded >=512 cyc ago: covered
        if (c + 1 < NCH) LOADB(B0, r8 + 8);    // next chunk kq0, behind kq0 FMAs
        FMABLK(B1, 1);
        if (c + 1 < NCH) {
            LOADB(B1, r8 + 12);                // next chunk kq1
            // chunk-c ds_reads must land before pane overwrite (same wave, in order)
            asm volatile("s_waitcnt lgkmcnt(0)" ::: "memory");
            STOREA();
        }
    }
#undef LOADA
#undef STOREA
#undef LOADB
#undef FMABLK

    // ssq: combine the two k-half lanes of each token (lanes 2t, 2t+1)
    ssq0 += __shfl_xor(ssq0, 1, 64);
    ssq1 += __shfl_xor(ssq1, 1, 64);
    if (ah == 0) {
        sq[(size_t)ks * tokens + tokw0 + atok] = ssq0;
        sq[(size_t)ks * tokens + tokw0 + 32 + atok] = ssq1;
    }

    float* sp = (ks == 0) ? sp0 : (spws + (size_t)(ks - 1) * tokens * NE);
    #pragma unroll
    for (int i = 0; i < 8; ++i) {      // token 8i+tr, experts 8ec..8ec+7
        size_t off = (size_t)(tokw0 + 8 * i + tr) * NE + 8 * ec;
        float4 v0 = {acc[i][0], acc[i][1], acc[i][2], acc[i][3]};
        float4 v1 = {acc[i][4], acc[i][5], acc[i][6], acc[i][7]};
        *(float4*)(sp + off) = v0;
        *(float4*)(sp + off + 4) = v1;
    }
}

// ---------- finisher: tree-sum KS partials, rmsnorm, softmax, top-4 ----------
template<int KS>
__global__ __launch_bounds__(256) void finish13_kernel(
    const float* __restrict__ sp0, const float* __restrict__ spws,
    const float* __restrict__ sq, const float* __restrict__ pes,
    float* __restrict__ probs, float* __restrict__ tkw, float* __restrict__ tki,
    int tokens)
{
    __shared__ float Sl[BM2 * 65];
    __shared__ float Pl[BM2 * 65];
    __shared__ float FN[BM2];
    __shared__ float RS[BM2];

    const int tid = threadIdx.x;
    const int tok0 = blockIdx.x * BM2;

    if (tid < BM2) {
        float q[KS];
        #pragma unroll
        for (int i = 0; i < KS; i++) q[i] = sq[(size_t)i * tokens + tok0 + tid];
        #pragma unroll
        for (int st = 1; st < KS; st <<= 1)
            #pragma unroll
            for (int i = 0; i < KS; i += 2 * st) q[i] += q[i + st];
        FN[tid] = rsqrtf(q[0] * (1.0f / HDIM) + 1e-6f) * 0.022097086912079612f;
    }
    __syncthreads();

    #pragma unroll
    for (int qq = 0; qq < 2; qq++) {
        int f = tid + 256 * qq;
        int m = f >> 4;
        int e4 = f & 15;
        float4 t[KS];
        t[0] = ((const float4*)sp0)[(size_t)(tok0 + m) * (NE / 4) + e4];
        #pragma unroll
        for (int i = 1; i < KS; i++)
            t[i] = ((const float4*)(spws + (size_t)(i - 1) * tokens * NE))
                       [(size_t)(tok0 + m) * (NE / 4) + e4];
        #pragma unroll
        for (int st = 1; st < KS; st <<= 1)
            #pragma unroll
            for (int i = 0; i < KS; i += 2 * st) {
                t[i].x += t[i + st].x; t[i].y += t[i + st].y;
                t[i].z += t[i + st].z; t[i].w += t[i + st].w;
            }
        float fn = FN[m];
        int base = m * 65 + e4 * 4;
        Sl[base + 0] = t[0].x * fn; Sl[base + 1] = t[0].y * fn;
        Sl[base + 2] = t[0].z * fn; Sl[base + 3] = t[0].w * fn;
    }
    __syncthreads();

    if (tid < BM2) {
        const int m = tid;
        float mx = -3.0e38f;
        for (int e = 0; e < NE; e++) mx = fmaxf(mx, Sl[m * 65 + e]);
        float sum = 0.f;
        for (int e = 0; e < NE; e++) {
            float p = __expf(Sl[m * 65 + e] - mx);
            Pl[m * 65 + e] = p;
            sum += p;
        }
        RS[m] = 1.0f / sum;
    }
    __syncthreads();

    #pragma unroll
    for (int qq = 0; qq < 2; qq++) {
        int f = tid + 256 * qq;
        int m = f >> 4;
        int e0 = (f & 15) * 4;
        float rs = RS[m];
        float4 pv;
        pv.x = Pl[m * 65 + e0 + 0] * rs;
        pv.y = Pl[m * 65 + e0 + 1] * rs;
        pv.z = Pl[m * 65 + e0 + 2] * rs;
        pv.w = Pl[m * 65 + e0 + 3] * rs;
        *(float4*)&probs[(size_t)(tok0 + m) * NE + e0] = pv;
    }

    if (tid < BM2) {                   // destructive top-4, lowest-index ties
        const int m = tid;
        float wv[TOPK]; int idx[TOPK];
        float wsum = 0.f;
        #pragma unroll
        for (int kk = 0; kk < TOPK; ++kk) {
            float best = -3.0e38f; int bi = 0;
            for (int e = 0; e < NE; e++) {
                float v = Sl[m * 65 + e];
                if (v > best) { best = v; bi = e; }
            }
            Sl[m * 65 + bi] = -3.4e38f;
            float p = Pl[m * 65 + bi];
            wv[kk] = p; idx[kk] = bi; wsum += p;
        }
        float inv = 1.0f / wsum;
        size_t ob = (size_t)(tok0 + m) * TOPK;
        #pragma unroll
        for (int kk = 0; kk < TOPK; kk++) {
            tkw[ob + kk] = wv[kk] * inv * pes[idx[kk]];
            tki[ob + kk] = (float)idx[kk];   // harness reads flat buffer as float32
        }
    }
}

extern "C" void kernel_launch(void* const* d_in, const int* in_sizes, int n_in,
                              void* d_out, int out_size, void* d_ws, size_t ws_size,
                              hipStream_t stream) {
    const float* x     = (const float*)d_in[0];
    const float* w     = (const float*)d_in[1];
    const float* scale = (const float*)d_in[2];
    const float* pes   = (const float*)d_in[3];
    const int tokens = in_sizes[0] / HDIM;      // 16384

    float* probs = (float*)d_out;
    float* tkw   = probs + (size_t)tokens * NE;
    float* tki   = tkw + (size_t)tokens * TOPK;

    const size_t wtN = (size_t)HDIM * NE;
    const size_t spN = (size_t)tokens * NE;
    const size_t need8 = (wtN + 7 * spN + (size_t)8 * tokens) * sizeof(float);
    const int KS = (ws_size >= need8) ? 8 : 4;

    float* wt   = (float*)d_ws;
    float* spws = wt + wtN;
    float* sq   = spws + (size_t)(KS - 1) * spN;
    float* sp0  = probs;                        // overwritten by finisher

    transpose_w_kernel<<<HDIM / 64, 256, 0, stream>>>(w, scale, wt);

    const int grid1 = (tokens / 512) * KS;      // 256 @ KS=8 -> 1 block/CU
    if (KS == 8)
        gemm13_kernel<8><<<grid1, 512, 0, stream>>>(x, wt, sp0, spws, sq, tokens);
    else
        gemm13_kernel<4><<<grid1, 512, 0, stream>>>(x, wt, sp0, spws, sq, tokens);

    const int grid2 = tokens / BM2;             // 512
    if (KS == 8)
        finish13_kernel<8><<<grid2, 256, 0, stream>>>(sp0, spws, sq, pes, probs, tkw, tki, tokens);
    else
        finish13_kernel<4><<<grid2, 256, 0, stream>>>(sp0, spws, sq, pes, probs, tkw, tki, tokens);
}